// Round 4
// baseline (237.515 us; speedup 1.0000x reference)
//
#include <hip/hip_runtime.h>

namespace {

constexpr int LEN   = 160;
constexpr int PLANE = LEN * LEN;            // 25600
constexpr int VOL   = LEN * PLANE;          // 4,096,000 per batch
constexpr float INV_SZ = 1.0f / 125.0f;
constexpr float EPS_   = 1e-10f;

constexpr int TX = 32, TY = 32, ZC = 8;     // output tile (ZC=8 -> 1000 blocks)
constexpr int RY = TY + 4;                  // 36 halo rows
constexpr int RW = 40;                      // padded halo row: [x0-4, x0+36)
constexpr int NXS   = TX * RY;              // 1152 x-sum outputs/plane
constexpr int NCORE = (TX / 4) * RY;        // 288 float4 core loads/field/plane
constexpr int NCHZ  = LEN / ZC;             // 20 z-chunks
constexpr int BLK   = 512;                  // 2 output px / thread

__device__ __forceinline__ int clampi(int v) {
  return v < 0 ? 0 : (v > LEN - 1 ? LEN - 1 : v);
}

// ---------------------------------------------------------------------------
// Two-field slab box3, software-pipelined, float4 core halo loads.
// MODE 0: outA = inA - box3(inA)/125 ; outB likewise.
// MODE 1: raw holds unsquared values, xs squares on read;
//   outA = (inA/(sqrt(box3(inA^2)/125)+eps)) * (inB/(sqrt(box3(inB^2)/125)+eps))
// ---------------------------------------------------------------------------
template <int MODE>
__global__ __launch_bounds__(BLK) void slab2(const float* __restrict__ inA,
                                             const float* __restrict__ inB,
                                             float* __restrict__ outA,
                                             float* __restrict__ outB) {
  __shared__ float rawA[RY][RW], rawB[RY][RW];   // 11.5 KB
  __shared__ float xsA[RY][TX],  xsB[RY][TX];    //  9.2 KB

  const int tid = threadIdx.x;
  const int x0 = blockIdx.x * TX;
  const int y0 = blockIdx.y * TY;
  const int z0 = (blockIdx.z % NCHZ) * ZC;
  const size_t base = (size_t)(blockIdx.z / NCHZ) * VOL;

  // ---- plane-invariant load descriptors ----
  const bool isCore = tid < NCORE;
  int coreOff = 0, coreRow = 0, coreC = 0;
  int eOff[2] = {0, 0}, eRow[2] = {0, 0}, eLx[2] = {2, 2};
  bool eIsB[2] = {false, false}, eVal[2] = {false, false};
  if (isCore) {
    coreRow = tid >> 3; coreC = tid & 7;               // 36 rows x 8 float4s
    coreOff = clampi(y0 - 2 + coreRow) * LEN + (x0 + 4 * coreC);
  } else {
    int e = tid - NCORE;                               // 0..223, 288 edge items (A+B)
#pragma unroll
    for (int s = 0; s < 2; ++s) {
      int ee = e + s * 224;
      eVal[s] = ee < 288;
      int ee2 = eVal[s] ? ee : 0;
      eIsB[s] = ee2 >= 144;
      int pos = eIsB[s] ? ee2 - 144 : ee2;
      eRow[s] = pos >> 2;
      int c = pos & 3;
      eLx[s] = (c < 2) ? (2 + c) : (34 + c);           // lx in {2,3,36,37}
      eOff[s] = clampi(y0 - 2 + eRow[s]) * LEN + clampi(x0 - 4 + eLx[s]);
    }
  }

  // owned output pixels
  const int ly0 = tid >> 5,         lx0 = tid & 31;
  const int ly1 = (tid + BLK) >> 5, lx1 = (tid + BLK) & 31;

  float4 cA, cB;               // prefetched core float4s
  float  ev[2];                // prefetched edge scalars
  float rzA[5][2], rzB[5][2];  // z-ring of xy-sums
  float cenA[3][2], cenB[3][2];// center ring, lag 2

  auto loadPlane = [&](int zp) {
    const size_t pb = base + (size_t)clampi(zp) * PLANE;
    if (isCore) {
      cA = *(const float4*)(inA + pb + coreOff);
      cB = *(const float4*)(inB + pb + coreOff);
    } else {
#pragma unroll
      for (int s = 0; s < 2; ++s)
        if (eVal[s]) ev[s] = (eIsB[s] ? inB : inA)[pb + eOff[s]];
    }
  };
  auto depositLDS = [&]() {
    if (isCore) {
      *(float4*)&rawA[coreRow][4 + 4 * coreC] = cA;
      *(float4*)&rawB[coreRow][4 + 4 * coreC] = cB;
    } else {
#pragma unroll
      for (int s = 0; s < 2; ++s)
        if (eVal[s]) (eIsB[s] ? rawB : rawA)[eRow[s]][eLx[s]] = ev[s];
    }
  };

  loadPlane(z0 - 2);
  depositLDS();
  __syncthreads();

  for (int zp = z0 - 2; zp <= z0 + ZC + 1; ++zp) {
    if (zp <= z0 + ZC) loadPlane(zp + 1);   // prefetch in flight during compute

    // x-sums from raw (square on read for MODE 1)
#pragma unroll
    for (int j = 0; j < 3; ++j) {
      int i = tid + j * BLK;
      if (i < NXS) {
        int ly = i >> 5, lx = i & 31;
        float sa = 0.f, sb = 0.f;
#pragma unroll
        for (int k = 0; k < 5; ++k) {
          float a = rawA[ly][lx + 2 + k], b = rawB[ly][lx + 2 + k];
          if (MODE == 1) { a *= a; b *= b; }
          sa += a; sb += b;
        }
        xsA[ly][lx] = sa; xsB[ly][lx] = sb;
      }
    }
    // center stash (unsquared), ring shift: cen[0] = lag-2 value
#pragma unroll
    for (int s = 0; s < 2; ++s)
#pragma unroll
      for (int p = 0; p < 2; ++p) {
        cenA[s][p] = cenA[s + 1][p]; cenB[s][p] = cenB[s + 1][p];
      }
    cenA[2][0] = rawA[ly0 + 2][lx0 + 4]; cenB[2][0] = rawB[ly0 + 2][lx0 + 4];
    cenA[2][1] = rawA[ly1 + 2][lx1 + 4]; cenB[2][1] = rawB[ly1 + 2][lx1 + 4];

    __syncthreads();                        // raw reads done; xs visible

    if (zp <= z0 + ZC) depositLDS();        // raw <- plane zp+1

    // y-sums into register z-ring
#pragma unroll
    for (int s = 0; s < 4; ++s)
#pragma unroll
      for (int p = 0; p < 2; ++p) {
        rzA[s][p] = rzA[s + 1][p]; rzB[s][p] = rzB[s + 1][p];
      }
    {
      float sa0 = 0.f, sb0 = 0.f, sa1 = 0.f, sb1 = 0.f;
#pragma unroll
      for (int k = 0; k < 5; ++k) {
        sa0 += xsA[ly0 + k][lx0]; sb0 += xsB[ly0 + k][lx0];
        sa1 += xsA[ly1 + k][lx1]; sb1 += xsB[ly1 + k][lx1];
      }
      rzA[4][0] = sa0; rzB[4][0] = sb0; rzA[4][1] = sa1; rzB[4][1] = sb1;
    }

    if (zp >= z0 + 2) {
      const int zo = zp - 2;
      float bsA0 = 0.f, bsB0 = 0.f, bsA1 = 0.f, bsB1 = 0.f;
#pragma unroll
      for (int s = 0; s < 5; ++s) {
        bsA0 += rzA[s][0]; bsB0 += rzB[s][0];
        bsA1 += rzA[s][1]; bsB1 += rzB[s][1];
      }
      size_t g0 = base + (size_t)zo * PLANE + (size_t)(y0 + ly0) * LEN + (x0 + lx0);
      size_t g1 = base + (size_t)zo * PLANE + (size_t)(y0 + ly1) * LEN + (x0 + lx1);
      if (MODE == 0) {
        outA[g0] = cenA[0][0] - bsA0 * INV_SZ;
        outB[g0] = cenB[0][0] - bsB0 * INV_SZ;
        outA[g1] = cenA[0][1] - bsA1 * INV_SZ;
        outB[g1] = cenB[0][1] - bsB1 * INV_SZ;
      } else {
        float sF0 = sqrtf(bsA0 * INV_SZ) + EPS_, sM0 = sqrtf(bsB0 * INV_SZ) + EPS_;
        float sF1 = sqrtf(bsA1 * INV_SZ) + EPS_, sM1 = sqrtf(bsB1 * INV_SZ) + EPS_;
        outA[g0] = (cenA[0][0] / sF0) * (cenB[0][0] / sM0);
        outA[g1] = (cenA[0][1] / sF1) * (cenB[0][1] / sM1);
      }
    }
    __syncthreads();                        // raw(zp+1) ready; xs reads done
  }
}

// ---------------------------------------------------------------------------
// Stage C: cross = box3(p); acc += cross^2 * mask; block reduce -> atomicAdd.
// ---------------------------------------------------------------------------
__global__ __launch_bounds__(BLK) void slab1_reduce(const float* __restrict__ p,
                                                    const float* __restrict__ mask,
                                                    float* __restrict__ out) {
  __shared__ float raw[RY][RW];
  __shared__ float xs[RY][TX];
  __shared__ float wsum[BLK / 64];

  const int tid = threadIdx.x;
  const int x0 = blockIdx.x * TX;
  const int y0 = blockIdx.y * TY;
  const int z0 = (blockIdx.z % NCHZ) * ZC;
  const size_t base = (size_t)(blockIdx.z / NCHZ) * VOL;

  const bool isCore = tid < NCORE;
  const bool isEdge = !isCore && tid < NCORE + 144;
  int coreOff = 0, coreRow = 0, coreC = 0;
  int eOff = 0, eRow = 0, eLx = 2;
  if (isCore) {
    coreRow = tid >> 3; coreC = tid & 7;
    coreOff = clampi(y0 - 2 + coreRow) * LEN + (x0 + 4 * coreC);
  } else if (isEdge) {
    int pos = tid - NCORE;           // 0..143
    eRow = pos >> 2;
    int c = pos & 3;
    eLx = (c < 2) ? (2 + c) : (34 + c);
    eOff = clampi(y0 - 2 + eRow) * LEN + clampi(x0 - 4 + eLx);
  }

  const int ly0 = tid >> 5,         lx0 = tid & 31;
  const int ly1 = (tid + BLK) >> 5, lx1 = (tid + BLK) & 31;

  float4 cP; float eP = 0.f;
  float rz[5][2];
  float acc = 0.f;

  auto loadPlane = [&](int zp) {
    const size_t pb = base + (size_t)clampi(zp) * PLANE;
    if (isCore)      cP = *(const float4*)(p + pb + coreOff);
    else if (isEdge) eP = p[pb + eOff];
  };
  auto depositLDS = [&]() {
    if (isCore)      *(float4*)&raw[coreRow][4 + 4 * coreC] = cP;
    else if (isEdge) raw[eRow][eLx] = eP;
  };

  loadPlane(z0 - 2);
  depositLDS();
  __syncthreads();

  for (int zp = z0 - 2; zp <= z0 + ZC + 1; ++zp) {
    if (zp <= z0 + ZC) loadPlane(zp + 1);

#pragma unroll
    for (int j = 0; j < 3; ++j) {
      int i = tid + j * BLK;
      if (i < NXS) {
        int ly = i >> 5, lx = i & 31;
        float s = 0.f;
#pragma unroll
        for (int k = 0; k < 5; ++k) s += raw[ly][lx + 2 + k];
        xs[ly][lx] = s;
      }
    }
    __syncthreads();

    if (zp <= z0 + ZC) depositLDS();

#pragma unroll
    for (int s = 0; s < 4; ++s)
#pragma unroll
      for (int px = 0; px < 2; ++px) rz[s][px] = rz[s + 1][px];
    {
      float s0 = 0.f, s1 = 0.f;
#pragma unroll
      for (int k = 0; k < 5; ++k) { s0 += xs[ly0 + k][lx0]; s1 += xs[ly1 + k][lx1]; }
      rz[4][0] = s0; rz[4][1] = s1;
    }

    if (zp >= z0 + 2) {
      const int zo = zp - 2;
      float bs0 = 0.f, bs1 = 0.f;
#pragma unroll
      for (int s = 0; s < 5; ++s) { bs0 += rz[s][0]; bs1 += rz[s][1]; }
      size_t g0 = base + (size_t)zo * PLANE + (size_t)(y0 + ly0) * LEN + (x0 + lx0);
      size_t g1 = base + (size_t)zo * PLANE + (size_t)(y0 + ly1) * LEN + (x0 + lx1);
      acc += bs0 * bs0 * mask[g0];
      acc += bs1 * bs1 * mask[g1];
    }
    __syncthreads();
  }

#pragma unroll
  for (int o = 32; o > 0; o >>= 1) acc += __shfl_down(acc, o, 64);
  int lane = tid & 63, wid = tid >> 6;
  if (lane == 0) wsum[wid] = acc;
  __syncthreads();
  if (tid == 0) {
    float t = 0.f;
#pragma unroll
    for (int w = 0; w < BLK / 64; ++w) t += wsum[w];
    atomicAdd(out, -t);
  }
}

}  // namespace

extern "C" void kernel_launch(void* const* d_in, const int* in_sizes, int n_in,
                              void* d_out, int out_size, void* d_ws, size_t ws_size,
                              hipStream_t stream) {
  const float* F    = (const float*)d_in[0];
  const float* M    = (const float*)d_in[1];
  const float* mask = (const float*)d_in[2];
  float* out = (float*)d_out;

  const size_t bufB = (size_t)(2 * VOL) * sizeof(float);
  char* ws = (char*)d_ws;
  float* dF = (float*)ws;
  float* dM = (float*)(ws + bufB);
  float* pB = (float*)(ws + 2 * bufB);

  hipMemsetAsync(d_out, 0, sizeof(float), stream);

  dim3 grd(LEN / TX, LEN / TY, NCHZ * 2), blk(BLK);

  slab2<0><<<grd, blk, 0, stream>>>(F, M, dF, dM);
  slab2<1><<<grd, blk, 0, stream>>>(dF, dM, pB, nullptr);
  slab1_reduce<<<grd, blk, 0, stream>>>(pB, mask, out);
}

// Round 7
// 225.992 us; speedup vs baseline: 1.0510x; 1.0510x over previous
//
#include <hip/hip_runtime.h>

namespace {

constexpr int LEN   = 160;
constexpr int PLANE = LEN * LEN;
constexpr int VOL   = LEN * PLANE;
constexpr float INV_SZ = 1.0f / 125.0f;
constexpr float EPS_   = 1e-10f;

constexpr int TX = 32, TY = 32, ZC = 8;
constexpr int RY = 36, RW = 40;    // raw tile rows / padded width (cols 2..37 valid)
constexpr int XSW = 36;            // xs row stride (pad from 32: avoid 8-way conflicts)
constexpr int NCHZ = LEN / ZC;     // 20
constexpr int BLK = 256;           // thread owns a 4-px x-quad

__device__ __forceinline__ int clampi(int v) {
  return v < 0 ? 0 : (v > LEN - 1 ? LEN - 1 : v);
}
__device__ __forceinline__ float4 ld4(const float* p) { return *(const float4*)p; }
__device__ __forceinline__ void st4(float* p, float4 v) { *(float4*)p = v; }
__device__ __forceinline__ float4 f4add(float4 a, float4 b) {
  return make_float4(a.x + b.x, a.y + b.y, a.z + b.z, a.w + b.w);
}
__device__ __forceinline__ float rcp_(float x) { return __builtin_amdgcn_rcpf(x); }

// x-sum for one row-quad: 3 aligned b128 reads -> 4 sliding 5-tap sums.
template <int SQ>
__device__ __forceinline__ float4 xquad(const float (*raw)[RW], int row, int q) {
  float4 a0 = ld4(&raw[row][4 * q]);
  float4 a1 = ld4(&raw[row][4 * q + 4]);
  float4 a2 = ld4(&raw[row][4 * q + 8]);
  float f2 = a0.z, f3 = a0.w, f4 = a1.x, f5 = a1.y, f6 = a1.z, f7 = a1.w,
        f8 = a2.x, f9 = a2.y;
  if (SQ) { f2 *= f2; f3 *= f3; f4 *= f4; f5 *= f5; f6 *= f6; f7 *= f7; f8 *= f8; f9 *= f9; }
  float s0 = f2 + f3 + f4 + f5 + f6;
  float s1 = s0 - f2 + f7;
  float s2 = s1 - f3 + f8;
  float s3 = s2 - f4 + f9;
  return make_float4(s0, s1, s2, s3);
}

// ---------------------------------------------------------------------------
// Two-field slab box3, quad-per-thread, runtime z-loop, explicit ring shifts.
// MODE 0: outA = inA - box3(inA)/125 ; outB likewise.
// MODE 1: outA = (inA/(sqrt(box3(inA^2)/125)+eps))*(inB/(sqrt(box3(inB^2)/125)+eps))
// ---------------------------------------------------------------------------
template <int MODE>
__global__ __launch_bounds__(BLK, 2) void slab2(const float* __restrict__ inA,
                                                const float* __restrict__ inB,
                                                float* __restrict__ outA,
                                                float* __restrict__ outB) {
  __shared__ float rawA[RY][RW], rawB[RY][RW];
  __shared__ float xsA[RY][XSW], xsB[RY][XSW];

  const int tid = threadIdx.x;
  const int x0 = blockIdx.x * TX, y0 = blockIdx.y * TY;
  const int z0 = (blockIdx.z % NCHZ) * ZC;
  const size_t base = (size_t)(blockIdx.z / NCHZ) * VOL;

  const int row0 = tid >> 3, q0 = tid & 7;      // owned quad; core/xs task 0
  const int row1 = 32 + (tid >> 3);             // core/xs task 1 (tid<32)
  const int off0 = clampi(y0 - 2 + row0) * LEN + x0 + 4 * q0;
  const int off1 = (tid < 32) ? clampi(y0 - 2 + row1) * LEN + x0 + 4 * q0 : 0;

  // edge scalars: 144 per field (36 rows x cols {2,3,36,37})
  const bool hasEA = tid < 144;
  const bool hasEB = (tid >= 144) || (tid < 32);
  const int pa = hasEA ? tid : 0;
  const int erA = pa >> 2, ccA = pa & 3;
  const int elA = ccA < 2 ? 2 + ccA : 34 + ccA;
  const int eoffA = clampi(y0 - 2 + erA) * LEN + clampi(x0 + elA - 4);
  const int pb_ = hasEB ? (tid >= 144 ? tid - 144 : 112 + tid) : 0;
  const int erB = pb_ >> 2, ccB = pb_ & 3;
  const int elB = ccB < 2 ? 2 + ccB : 34 + ccB;
  const int eoffB = clampi(y0 - 2 + erB) * LEN + clampi(x0 + elB - 4);

  float4 pA0, pB0, pA1, pB1;
  float eA = 0.f, eB = 0.f;
  float4 rA0, rA1, rA2, rA3, rA4, rB0, rB1, rB2, rB3, rB4;   // ys z-ring
  float4 cA0, cA1, cA2, cB0, cB1, cB2;                       // center ring (lag 2)
  rA0 = rA1 = rA2 = rA3 = rA4 = make_float4(0.f, 0.f, 0.f, 0.f);
  rB0 = rB1 = rB2 = rB3 = rB4 = rA0;
  cA0 = cA1 = cA2 = cB0 = cB1 = cB2 = rA0;

  auto loadPlane = [&](int zp) {
    const size_t pbz = base + (size_t)clampi(zp) * PLANE;
    pA0 = ld4(inA + pbz + off0);
    pB0 = ld4(inB + pbz + off0);
    if (tid < 32) { pA1 = ld4(inA + pbz + off1); pB1 = ld4(inB + pbz + off1); }
    if (hasEA) eA = inA[pbz + eoffA];
    if (hasEB) eB = inB[pbz + eoffB];
  };
  auto deposit = [&]() {
    st4(&rawA[row0][4 + 4 * q0], pA0);
    st4(&rawB[row0][4 + 4 * q0], pB0);
    if (tid < 32) { st4(&rawA[row1][4 + 4 * q0], pA1); st4(&rawB[row1][4 + 4 * q0], pB1); }
    if (hasEA) rawA[erA][elA] = eA;
    if (hasEB) rawB[erB][elB] = eB;
  };

  loadPlane(z0 - 2);
  deposit();
  __syncthreads();

  for (int zp = z0 - 2; zp <= z0 + ZC + 1; ++zp) {
    if (zp <= z0 + ZC) loadPlane(zp + 1);   // prefetch next plane into registers

    // x-sums of plane zp (square on read for MODE 1)
    st4(&xsA[row0][4 * q0], xquad<MODE == 1>(rawA, row0, q0));
    st4(&xsB[row0][4 * q0], xquad<MODE == 1>(rawB, row0, q0));
    if (tid < 32) {
      st4(&xsA[row1][4 * q0], xquad<MODE == 1>(rawA, row1, q0));
      st4(&xsB[row1][4 * q0], xquad<MODE == 1>(rawB, row1, q0));
    }
    // center ring shift + stash (unsquared raw)
    cA0 = cA1; cA1 = cA2; cA2 = ld4(&rawA[row0 + 2][4 * q0 + 4]);
    cB0 = cB1; cB1 = cB2; cB2 = ld4(&rawB[row0 + 2][4 * q0 + 4]);

    __syncthreads();            // raw consumed; xs published

    if (zp <= z0 + ZC) deposit();  // raw <- plane zp+1

    // y-sums of plane zp
    float4 ysA = make_float4(0.f, 0.f, 0.f, 0.f), ysB = ysA;
#pragma unroll
    for (int k = 0; k < 5; ++k) {
      ysA = f4add(ysA, ld4(&xsA[row0 + k][4 * q0]));
      ysB = f4add(ysB, ld4(&xsB[row0 + k][4 * q0]));
    }
    // z-ring shift
    rA0 = rA1; rA1 = rA2; rA2 = rA3; rA3 = rA4; rA4 = ysA;
    rB0 = rB1; rB1 = rB2; rB2 = rB3; rB3 = rB4; rB4 = ysB;

    if (zp >= z0 + 2) {
      const int zo = zp - 2;
      float4 bsA = f4add(f4add(f4add(rA0, rA1), f4add(rA2, rA3)), rA4);
      float4 bsB = f4add(f4add(f4add(rB0, rB1), f4add(rB2, rB3)), rB4);
      size_t g = base + (size_t)zo * PLANE + (size_t)(y0 + row0) * LEN + (x0 + 4 * q0);
      if (MODE == 0) {
        st4(outA + g, make_float4(cA0.x - bsA.x * INV_SZ, cA0.y - bsA.y * INV_SZ,
                                  cA0.z - bsA.z * INV_SZ, cA0.w - bsA.w * INV_SZ));
        st4(outB + g, make_float4(cB0.x - bsB.x * INV_SZ, cB0.y - bsB.y * INV_SZ,
                                  cB0.z - bsB.z * INV_SZ, cB0.w - bsB.w * INV_SZ));
      } else {
        float4 o;
        o.x = (cA0.x * rcp_(sqrtf(bsA.x * INV_SZ) + EPS_)) * (cB0.x * rcp_(sqrtf(bsB.x * INV_SZ) + EPS_));
        o.y = (cA0.y * rcp_(sqrtf(bsA.y * INV_SZ) + EPS_)) * (cB0.y * rcp_(sqrtf(bsB.y * INV_SZ) + EPS_));
        o.z = (cA0.z * rcp_(sqrtf(bsA.z * INV_SZ) + EPS_)) * (cB0.z * rcp_(sqrtf(bsB.z * INV_SZ) + EPS_));
        o.w = (cA0.w * rcp_(sqrtf(bsA.w * INV_SZ) + EPS_)) * (cB0.w * rcp_(sqrtf(bsB.w * INV_SZ) + EPS_));
        st4(outA + g, o);
      }
    }
    __syncthreads();            // xs consumed; raw(zp+1) published
  }
}

// ---------------------------------------------------------------------------
// Stage C: cross = box3(p); acc += cross^2 * mask; block reduce -> atomicAdd.
// ---------------------------------------------------------------------------
__global__ __launch_bounds__(BLK, 2) void slab1_reduce(const float* __restrict__ p,
                                                       const float* __restrict__ mask,
                                                       float* __restrict__ out) {
  __shared__ float raw[RY][RW];
  __shared__ float xs[RY][XSW];
  __shared__ float wsum[BLK / 64];

  const int tid = threadIdx.x;
  const int x0 = blockIdx.x * TX, y0 = blockIdx.y * TY;
  const int z0 = (blockIdx.z % NCHZ) * ZC;
  const size_t base = (size_t)(blockIdx.z / NCHZ) * VOL;

  const int row0 = tid >> 3, q0 = tid & 7;
  const int row1 = 32 + (tid >> 3);
  const int off0 = clampi(y0 - 2 + row0) * LEN + x0 + 4 * q0;
  const int off1 = (tid < 32) ? clampi(y0 - 2 + row1) * LEN + x0 + 4 * q0 : 0;

  const bool hasE = tid < 144;
  const int pe = hasE ? tid : 0;
  const int er = pe >> 2, ce = pe & 3;
  const int el = ce < 2 ? 2 + ce : 34 + ce;
  const int eoff = clampi(y0 - 2 + er) * LEN + clampi(x0 + el - 4);

  float4 pc0, pc1;
  float ev = 0.f;
  float4 r0, r1, r2, r3, r4;
  r0 = r1 = r2 = r3 = r4 = make_float4(0.f, 0.f, 0.f, 0.f);
  float acc = 0.f;

  auto loadPlane = [&](int zp) {
    const size_t pbz = base + (size_t)clampi(zp) * PLANE;
    pc0 = ld4(p + pbz + off0);
    if (tid < 32) pc1 = ld4(p + pbz + off1);
    if (hasE) ev = p[pbz + eoff];
  };
  auto deposit = [&]() {
    st4(&raw[row0][4 + 4 * q0], pc0);
    if (tid < 32) st4(&raw[row1][4 + 4 * q0], pc1);
    if (hasE) raw[er][el] = ev;
  };

  loadPlane(z0 - 2);
  deposit();
  __syncthreads();

  for (int zp = z0 - 2; zp <= z0 + ZC + 1; ++zp) {
    if (zp <= z0 + ZC) loadPlane(zp + 1);

    st4(&xs[row0][4 * q0], xquad<0>(raw, row0, q0));
    if (tid < 32) st4(&xs[row1][4 * q0], xquad<0>(raw, row1, q0));

    __syncthreads();

    if (zp <= z0 + ZC) deposit();

    float4 ys = make_float4(0.f, 0.f, 0.f, 0.f);
#pragma unroll
    for (int k = 0; k < 5; ++k) ys = f4add(ys, ld4(&xs[row0 + k][4 * q0]));
    r0 = r1; r1 = r2; r2 = r3; r3 = r4; r4 = ys;

    if (zp >= z0 + 2) {
      const int zo = zp - 2;
      float4 bs = f4add(f4add(f4add(r0, r1), f4add(r2, r3)), r4);
      size_t g = base + (size_t)zo * PLANE + (size_t)(y0 + row0) * LEN + (x0 + 4 * q0);
      float4 mk = ld4(mask + g);
      acc += bs.x * bs.x * mk.x + bs.y * bs.y * mk.y +
             bs.z * bs.z * mk.z + bs.w * bs.w * mk.w;
    }
    __syncthreads();
  }

#pragma unroll
  for (int o = 32; o > 0; o >>= 1) acc += __shfl_down(acc, o, 64);
  int lane = tid & 63, wid = tid >> 6;
  if (lane == 0) wsum[wid] = acc;
  __syncthreads();
  if (tid == 0) {
    float t = 0.f;
#pragma unroll
    for (int w = 0; w < BLK / 64; ++w) t += wsum[w];
    atomicAdd(out, -t);
  }
}

}  // namespace

extern "C" void kernel_launch(void* const* d_in, const int* in_sizes, int n_in,
                              void* d_out, int out_size, void* d_ws, size_t ws_size,
                              hipStream_t stream) {
  const float* F    = (const float*)d_in[0];
  const float* M    = (const float*)d_in[1];
  const float* mask = (const float*)d_in[2];
  float* out = (float*)d_out;

  const size_t bufB = (size_t)(2 * VOL) * sizeof(float);
  char* ws = (char*)d_ws;
  float* dF = (float*)ws;
  float* dM = (float*)(ws + bufB);
  float* pB = (float*)(ws + 2 * bufB);

  hipMemsetAsync(d_out, 0, sizeof(float), stream);

  dim3 grd(LEN / TX, LEN / TY, NCHZ * 2), blk(BLK);

  slab2<0><<<grd, blk, 0, stream>>>(F, M, dF, dM);
  slab2<1><<<grd, blk, 0, stream>>>(dF, dM, pB, nullptr);
  slab1_reduce<<<grd, blk, 0, stream>>>(pB, mask, out);
}